// Round 5
// baseline (449.783 us; speedup 1.0000x reference)
//
#include <hip/hip_runtime.h>
#include <math.h>

#define D 2048
#define E 64
#define TPW 8              // tokens per wave
#define KHALF (D / 2)      // 1024: K split across kh=0/1 wave pairs
#define TOKB 16            // tokens per block (2 token-groups x TPW)
#define THREADS 256        // 4 waves: w = (tg<<1)|kh

__device__ __forceinline__ float fget(const float4 v, int j) {
    return j == 0 ? v.x : j == 1 ? v.y : j == 2 ? v.z : v.w;
}

// Dataflow (round-4 post-mortem): lane = EXPERT, so the per-lane streamed
// operand is W (1 coalesced 256B dword-load per k-row, L2-resident, the ONLY
// vmcnt traffic -> clean partial vmcnt waits on an 8-row ring), and the splat
// operand is x (wave-uniform s_load_dwordx4 -> SGPRs -> v_fmac v,s,v; only
// 8 floats/row consumed -> one lgkmcnt(0) drain per 4-row window with a full
// window of cover). The two memory streams live on DIFFERENT counters, which
// rounds 0 and 4 proved is the whole game.
__global__ __launch_bounds__(THREADS)
void gating_kernel(const float* __restrict__ x,
                   const float* __restrict__ W,
                   const float* __restrict__ Bv,
                   float* __restrict__ out)
{
    __shared__ float lg[TOKB][72];     // stride 72: 64-lane row write = 2-way (free)
    __shared__ float sw1[TOKB], sw2[TOKB];
    __shared__ int   si1[TOKB], si2[TOKB];

    const int tid  = threadIdx.x;
    const int lane = tid & 63;
    const int w    = __builtin_amdgcn_readfirstlane(tid >> 6); // provably uniform
    const int kh   = w & 1;            // K half
    const int tg   = w >> 1;           // token group
    const int tok0 = blockIdx.x * TOKB;

    const float* xw = x + (size_t)(tok0 + tg * TPW) * D + kh * KHALF; // uniform
    const float* wp = W + (size_t)kh * KHALF * E + lane;              // per-lane

    float acc[TPW];
#pragma unroll
    for (int t = 0; t < TPW; ++t) acc[t] = 0.f;

    // x window double buffer in SGPRs: xa = k[0..3], xb = k[4..7] per token.
    float4 xa[TPW], xb[TPW];
#pragma unroll
    for (int t = 0; t < TPW; ++t) xa[t] = *(const float4*)(xw + t * D);
#pragma unroll
    for (int t = 0; t < TPW; ++t) xb[t] = *(const float4*)(xw + t * D + 4);

    // W ring buffer, 8 rows deep (per-row coalesced dword, vmcnt-pipelined).
    float wv[8];
#pragma unroll
    for (int r = 0; r < 8; ++r) wv[r] = wp[(size_t)r * E];

#pragma unroll 1
    for (int k0 = 0; k0 < KHALF; k0 += 8) {
        // phase A: rows k0..k0+3 from xa (entry drain covers xa AND xb,
        // both issued one full iteration ago)
#pragma unroll
        for (int j = 0; j < 4; ++j) {
            const float wr = wv[j];
#pragma unroll
            for (int t = 0; t < TPW; ++t)
                acc[t] = fmaf(fget(xa[t], j), wr, acc[t]);
            int r = k0 + j + 8;                 // ring refill 8 rows ahead
            if (r > KHALF - 1) r = KHALF - 1;
            wv[j] = wp[(size_t)r * E];
        }
        // xa refill for k0+8 (WAR on xa pins this after the phase-A reads,
        // giving the next-iteration drain a full phase of cover)
        {
            int nk = k0 + 8; if (nk > KHALF - 4) nk = KHALF - 4;
#pragma unroll
            for (int t = 0; t < TPW; ++t)
                xa[t] = *(const float4*)(xw + t * D + nk);
        }
        // phase B: rows k0+4..k0+7 from xb
#pragma unroll
        for (int j = 0; j < 4; ++j) {
            const float wr = wv[4 + j];
#pragma unroll
            for (int t = 0; t < TPW; ++t)
                acc[t] = fmaf(fget(xb[t], j), wr, acc[t]);
            int r = k0 + 4 + j + 8;
            if (r > KHALF - 1) r = KHALF - 1;
            wv[4 + j] = wp[(size_t)r * E];
        }
        // xb refill for k0+12
        {
            int nk = k0 + 12; if (nk > KHALF - 4) nk = KHALF - 4;
#pragma unroll
            for (int t = 0; t < TPW; ++t)
                xb[t] = *(const float4*)(xw + t * D + nk);
        }
    }

    // ---- K-half pair reduce in LDS (+bias), tiny: 16 tokens x 64 experts ----
    __syncthreads();
    if (kh == 1) {
#pragma unroll
        for (int t = 0; t < TPW; ++t)
            lg[tg * TPW + t][lane] = acc[t];
    }
    __syncthreads();
    if (kh == 0) {
        const float bv = Bv[lane];
#pragma unroll
        for (int t = 0; t < TPW; ++t)
            lg[tg * TPW + t][lane] += acc[t] + bv;
    }
    __syncthreads();

    // ---- top-2 scan (verified logic): lane = token, ascending strict '>' ----
    if (w == 0 && lane < TOKB) {
        float m1 = -3.4e38f, m2 = -3.4e38f;
        int i1 = 0, i2 = 0;
#pragma unroll
        for (int e = 0; e < E; ++e) {
            float v = lg[lane][e];
            if (v > m1)      { m2 = m1; i2 = i1; m1 = v; i1 = e; }
            else if (v > m2) { m2 = v; i2 = e; }
        }
        float p = 1.0f / (1.0f + expf(m2 - m1));   // stable: m2 <= m1
        sw1[lane] = p; sw2[lane] = 1.0f - p;
        si1[lane] = i1; si2[lane] = i2;
    }
    __syncthreads();

    // ---- coalesced float4 store: 16x64 tile = 256 float4 = blockDim ----
    float4* o4 = (float4*)(out + (size_t)tok0 * E);
    {
        int idx = tid;                  // 0..255
        int tl  = idx >> 4;             // token 0..15
        int e0  = (idx & 15) * 4;
        int a1 = si1[tl], a2 = si2[tl];
        float v1 = sw1[tl], v2 = sw2[tl];
        float4 v;
        v.x = (e0 + 0 == a1) ? v1 : (e0 + 0 == a2) ? v2 : 0.0f;
        v.y = (e0 + 1 == a1) ? v1 : (e0 + 1 == a2) ? v2 : 0.0f;
        v.z = (e0 + 2 == a1) ? v1 : (e0 + 2 == a2) ? v2 : 0.0f;
        v.w = (e0 + 3 == a1) ? v1 : (e0 + 3 == a2) ? v2 : 0.0f;
        o4[idx] = v;
    }
}

extern "C" void kernel_launch(void* const* d_in, const int* in_sizes, int n_in,
                              void* d_out, int out_size, void* d_ws, size_t ws_size,
                              hipStream_t stream) {
    const float* x = (const float*)d_in[0];
    const float* W = (const float*)d_in[1];
    const float* b = (const float*)d_in[2];
    float* out = (float*)d_out;

    const int tokens = in_sizes[0] / D;      // 16384
    const int blocks = tokens / TOKB;        // 1024

    gating_kernel<<<blocks, THREADS, 0, stream>>>(x, W, b, out);
}

// Round 6
// 300.554 us; speedup vs baseline: 1.4965x; 1.4965x over previous
//
#include <hip/hip_runtime.h>
#include <math.h>

#define D 2048
#define E 64
#define EQ 16                 // experts per wave (quarter)
#define TOK 64                // tokens per block (lane = token)
#define THREADS 1024          // 16 waves = 4 K-chunks x 4 expert quarters
#define NKC 4
#define KCH (D / NKC)         // 512 k-rows per wave
#define SROWS 16              // k-rows staged per step (1 KB per wave-slice buf)
#define NSTEP (KCH / SROWS)   // 32
#define TP 20                 // tree-tile row stride (floats): measured 0 conflicts

// 16 FMAs: acc[e] += xj * wb[e]  (all-VGPR v_fmac)
__device__ __forceinline__ void fmagrp(float (&acc)[EQ], float xj,
                                       const float4 (&wb)[4]) {
#pragma unroll
    for (int c = 0; c < 4; ++c) {
        acc[4*c+0] = fmaf(xj, wb[c].x, acc[4*c+0]);
        acc[4*c+1] = fmaf(xj, wb[c].y, acc[4*c+1]);
        acc[4*c+2] = fmaf(xj, wb[c].z, acc[4*c+2]);
        acc[4*c+3] = fmaf(xj, wb[c].w, acc[4*c+3]);
    }
}

// One W row (16 floats) from the wave's LDS slice: 4x ds_read_b128 at a
// wave-uniform address -> pure broadcast, conflict-free, partial-lgkmcnt
// pipelined by the compiler (m97-verified behavior).
__device__ __forceinline__ void ldrow(float4 (&dst)[4], const float* p) {
#pragma unroll
    for (int c = 0; c < 4; ++c) dst[c] = ((const float4*)p)[c];
}

// Reduction-tile IO (verified round-4 path, 0 bank conflicts at TP=20).
__device__ __forceinline__ void tile_write(float* t, const float (&a)[EQ], int lane) {
    float4* p = (float4*)(t + lane * TP);
#pragma unroll
    for (int c = 0; c < 4; ++c) {
        float4 v = {a[4*c], a[4*c+1], a[4*c+2], a[4*c+3]};
        p[c] = v;
    }
}

__device__ __forceinline__ void tile_add(const float* t, float (&a)[EQ], int lane) {
    const float4* p = (const float4*)(t + lane * TP);
#pragma unroll
    for (int c = 0; c < 4; ++c) {
        float4 v = p[c];
        a[4*c] += v.x; a[4*c+1] += v.y; a[4*c+2] += v.z; a[4*c+3] += v.w;
    }
}

// Dataflow (rounds 0-5 composed):
//  - x: per-lane float4 stream on vmcnt (round-0/4 proven, FETCH ~= 1.1x ideal).
//  - W: NEVER consumed straight from global/SMEM per row (that's the 25%/9%-duty
//    death in r0/r4/r5). Staged global->reg->LDS per 16-row step; all global
//    latency hidden behind a full step (~500+ cy) with PRECISE reg-dependency
//    vmcnt waits; per-row critical path is broadcast ds_read (~120 cy) covered
//    by a 2-row wb prefetch (~320 cy wall at 4 waves/SIMD).
__global__ __launch_bounds__(THREADS, 4)
void gating_kernel(const float* __restrict__ x,
                   const float* __restrict__ W,
                   const float* __restrict__ Bv,
                   float* __restrict__ out)
{
    // Union LDS (40 KB): [0..32KB) wave staging slices (2 bufs x 1 KB each),
    // then reused for the 8 tree tiles (t*1280 floats) + logits/top2 arrays.
    __shared__ __align__(16) float smem[10240];

    const int tid  = threadIdx.x;
    const int lane = tid & 63;
    const int w    = __builtin_amdgcn_readfirstlane(tid >> 6);
    const int eq   = w & 3;          // expert quarter (16 experts)
    const int kc   = w >> 2;         // K-chunk 0..3 (512 rows)
    const int tok0 = blockIdx.x * TOK;

    const float* xrow = x + (size_t)(tok0 + lane) * D + kc * KCH;  // per-lane

    // Stage source: lane covers element o=lane*4 of the 16x16 slice
    // (row = lane>>2, col = (lane&3)*4) -> coalesced dwordx4, L2-hot.
    const float* wsrc = W + ((size_t)kc * KCH + (lane >> 2)) * E
                          + eq * EQ + (lane & 3) * 4;

    float* slice = smem + w * (2 * SROWS * EQ);   // 512 floats: buf0|buf1

    float acc[EQ];
#pragma unroll
    for (int e = 0; e < EQ; ++e) acc[e] = 0.f;

    // ---- prologue: stage step 0, prefetch step 1, prime wb rows 0/1, x ----
    float4 wstg = *(const float4*)(wsrc);
    *((float4*)slice + lane) = wstg;                   // buf0 <- step 0
    wstg = *(const float4*)(wsrc + SROWS * E);         // step 1 in reg
    float4 wb[2][4];
    ldrow(wb[0], slice);                               // row 0
    ldrow(wb[1], slice + EQ);                          // row 1
    float4 xv = *(const float4*)(xrow);

#pragma unroll 1
    for (int s = 0; s < NSTEP; ++s) {
        float* bcur = slice + (s & 1) * (SROWS * EQ);
        float* bnxt = slice + ((s & 1) ^ 1) * (SROWS * EQ);
#pragma unroll
        for (int i = 0; i < 4; ++i) {                  // 4 k4-groups of 4 rows
            float4 xc = xv;
            int nk4 = s * 4 + i + 1;
            if (nk4 > KCH / 4 - 1) nk4 = KCH / 4 - 1;
            xv = *(const float4*)(xrow + nk4 * 4);
#pragma unroll
            for (int j = 0; j < 4; ++j) {
                const int k = i * 4 + j;               // row in step, 0..15
                const float xj = j == 0 ? xc.x : j == 1 ? xc.y
                               : j == 2 ? xc.z : xc.w;
                fmagrp(acc, xj, wb[k & 1]);
                const int pr = k + 2;                  // prefetch 2 rows ahead
                const float* src = (pr < SROWS) ? (bcur + pr * EQ)
                                                : (bnxt + (pr - SROWS) * EQ);
                ldrow(wb[k & 1], src);
            }
            if (i == 2) {
                // rows 0..11 done; write next step's slice BEFORE the k=14,15
                // cross-buffer prefetches (same-wave LDS ops stay in order).
                // wstg was loaded a full step ago -> precise vmcnt, no stall.
                *((float4*)bnxt + lane) = wstg;
                int ns = s + 2;
                if (ns > NSTEP - 1) ns = NSTEP - 1;
                wstg = *(const float4*)(wsrc + (size_t)ns * SROWS * E);
            }
        }
    }

    // ---- cross-wave K-reduction: 2-level tree (verified round-4 order) ----
    float* tiles = smem;                       // tile t at t*1280 floats
    __syncthreads();                           // staging slices now dead
    if (w >= 8) tile_write(tiles + (w - 8) * 64 * TP, acc, lane);
    __syncthreads();
    if (w < 8)  tile_add(tiles + w * 64 * TP, acc, lane);
    __syncthreads();
    if (w >= 4 && w < 8) tile_write(tiles + (w - 4) * 64 * TP, acc, lane);
    __syncthreads();
    if (w < 4)  tile_add(tiles + w * 64 * TP, acc, lane);
    __syncthreads();                                     // tiles now dead

    float* logits = smem;                      // [64][65]
    float* sw1 = (float*)((char*)smem + 16640);
    float* sw2 = (float*)((char*)smem + 16896);
    int*   si1 = (int*)  ((char*)smem + 17152);
    int*   si2 = (int*)  ((char*)smem + 17408);

    if (w < 4) {                               // write full logits tile
#pragma unroll
        for (int e = 0; e < EQ; ++e)
            logits[lane * 65 + eq * EQ + e] = acc[e];
    }
    __syncthreads();

    if (w == 0) {
        // lane = token: top-2 scan (+bias). Strict '>' matches top_k ties.
        float m1 = -3.4e38f, m2 = -3.4e38f;
        int i1 = 0, i2 = 0;
#pragma unroll
        for (int e = 0; e < E; ++e) {
            float v = logits[lane * 65 + e] + Bv[e];
            if (v > m1)      { m2 = m1; i2 = i1; m1 = v; i1 = e; }
            else if (v > m2) { m2 = v; i2 = e; }
        }
        float p = 1.0f / (1.0f + expf(m2 - m1));   // stable: m2 <= m1
        sw1[lane] = p; sw2[lane] = 1.0f - p;
        si1[lane] = i1; si2[lane] = i2;
    }
    __syncthreads();

    // ---- coalesced float4 store of the 64x64 tile (1024 float4) ----
    float4* o4 = (float4*)(out + (size_t)tok0 * E);
    {
        int idx = tid;                  // 0..1023
        int tl  = idx >> 4;             // token 0..63
        int e0  = (idx & 15) * 4;
        int a1 = si1[tl], a2 = si2[tl];
        float v1 = sw1[tl], v2 = sw2[tl];
        float4 v;
        v.x = (e0 + 0 == a1) ? v1 : (e0 + 0 == a2) ? v2 : 0.0f;
        v.y = (e0 + 1 == a1) ? v1 : (e0 + 1 == a2) ? v2 : 0.0f;
        v.z = (e0 + 2 == a1) ? v1 : (e0 + 2 == a2) ? v2 : 0.0f;
        v.w = (e0 + 3 == a1) ? v1 : (e0 + 3 == a2) ? v2 : 0.0f;
        o4[idx] = v;
    }
}

extern "C" void kernel_launch(void* const* d_in, const int* in_sizes, int n_in,
                              void* d_out, int out_size, void* d_ws, size_t ws_size,
                              hipStream_t stream) {
    const float* x = (const float*)d_in[0];
    const float* W = (const float*)d_in[1];
    const float* b = (const float*)d_in[2];
    float* out = (float*)d_out;

    const int tokens = in_sizes[0] / D;      // 16384
    const int blocks = tokens / TOK;         // 256

    gating_kernel<<<blocks, THREADS, 0, stream>>>(x, W, b, out);
}

// Round 7
// 251.621 us; speedup vs baseline: 1.7875x; 1.1945x over previous
//
#include <hip/hip_runtime.h>
#include <math.h>

#define D 2048
#define E 64
#define TOK 64                 // tokens per block
#define THREADS 256            // 4 waves = 4 K-quarters
#define NKC 4
#define KCH (D / NKC)          // 512 k-rows per wave
#define SK 16                  // k-rows per staged step
#define NSTEP (KCH / SK)       // 32

typedef float4 f4;

__device__ __forceinline__ float fget(const float4 v, int j) {
    return j == 0 ? v.x : j == 1 ? v.y : j == 2 ? v.z : v.w;
}

// 64 FMAs: outer product acc[8][8] += x8 (x) w8. All operands per-lane VGPRs.
__device__ __forceinline__ void fmablock(float (&acc)[8][8],
                                         const float4 (&xw)[2],
                                         const float4 (&ww)[2]) {
#pragma unroll
    for (int t = 0; t < 8; ++t) {
        const float xt = fget(t < 4 ? xw[0] : xw[1], t & 3);
#pragma unroll
        for (int e = 0; e < 8; ++e) {
            const float we = fget(e < 4 ? ww[0] : ww[1], e & 3);
            acc[t][e] = fmaf(xt, we, acc[t][e]);
        }
    }
}

// Tree-tile IO on [64 tok][65] fp32: lane (tg,eg) owns tokens tg*8+t,
// experts eg*8+e. 2x b128 per token row.
__device__ __forceinline__ void tile_store(float* b, const float (&acc)[8][8],
                                           int tg, int eg) {
#pragma unroll
    for (int t = 0; t < 8; ++t) {
        f4 v0 = {acc[t][0], acc[t][1], acc[t][2], acc[t][3]};
        f4 v1 = {acc[t][4], acc[t][5], acc[t][6], acc[t][7]};
        *(f4*)(b + (tg * 8 + t) * 65 + eg * 8) = v0;
        *(f4*)(b + (tg * 8 + t) * 65 + eg * 8 + 4) = v1;
    }
}

__device__ __forceinline__ void tile_addin(const float* b, float (&acc)[8][8],
                                           int tg, int eg) {
#pragma unroll
    for (int t = 0; t < 8; ++t) {
        f4 v0 = *(const f4*)(b + (tg * 8 + t) * 65 + eg * 8);
        f4 v1 = *(const f4*)(b + (tg * 8 + t) * 65 + eg * 8 + 4);
        acc[t][0] += v0.x; acc[t][1] += v0.y; acc[t][2] += v0.z; acc[t][3] += v0.w;
        acc[t][4] += v1.x; acc[t][5] += v1.y; acc[t][6] += v1.z; acc[t][7] += v1.w;
    }
}

// Round-6 post-mortem: uniform ds_read broadcast pays full return BW (64x
// amplification) -> 32k b128/block = 170 us. This kernel has NO splat stream:
// 2D register tile (lane = 8 tg x 8 eg, acc[8][8]); per k-row each lane reads
// 8 x-floats + 8 W-floats, all per-lane-distinct -> 4 b128/row/wave total,
// 8192 b128/block = the 41 us LDS floor. x is staged transposed so both reads
// are contiguous. Per-wave private staging slices -> NO barriers in the K-loop.
// LDS=64KB caps 2 blocks/CU -> 2 waves/EU class -> 256-VGPR budget (no spill).
__global__ __launch_bounds__(THREADS)
void gating_kernel(const float* __restrict__ x,
                   const float* __restrict__ W,
                   const float* __restrict__ Bv,
                   float* __restrict__ out)
{
    __shared__ __align__(16) float smem[16384];    // 64 KB

    const int tid  = threadIdx.x;
    const int lane = tid & 63;
    const int w    = __builtin_amdgcn_readfirstlane(tid >> 6);  // = kc 0..3
    const int tg   = lane >> 3;          // token group (8 tokens)
    const int eg   = lane & 7;           // expert group (8 experts)
    const int tok0 = blockIdx.x * TOK;

    // per-wave private staging slices (4 KB tiles, double buffered)
    float* base  = smem + w * 4096;
    float* xbuf0 = base;                 // xT [SK][64]
    float* xbuf1 = base + 1024;
    float* wbuf0 = base + 2048;          // W  [SK][64]
    float* wbuf1 = base + 3072;

    const float* xg = x + (size_t)(tok0 + lane) * D + w * KCH;  // lane=token (staging)
    const float* wg = W + (size_t)w * KCH * E;                  // [512][64]
    const int wr = lane >> 2, wq = lane & 3;                    // W staging role

    float acc[8][8];
#pragma unroll
    for (int t = 0; t < 8; ++t)
#pragma unroll
        for (int e = 0; e < 8; ++e) acc[t][e] = 0.f;

    float4 xs[4], ws[4];
    // ---- prologue: stage step 0, issue step-1 loads, prime rows 0/1 ----
#pragma unroll
    for (int c = 0; c < 4; ++c) xs[c] = *(const f4*)(xg + c * 4);
#pragma unroll
    for (int c = 0; c < 4; ++c)
        ws[c] = *(const f4*)(wg + (size_t)wr * E + (wq + c * 4) * 4);
#pragma unroll
    for (int j = 0; j < 16; ++j) xbuf0[j * 64 + lane] = fget(xs[j >> 2], j & 3);
#pragma unroll
    for (int c = 0; c < 4; ++c)
        *(f4*)(wbuf0 + wr * 64 + (wq + c * 4) * 4) = ws[c];
#pragma unroll
    for (int c = 0; c < 4; ++c) xs[c] = *(const f4*)(xg + SK + c * 4);
#pragma unroll
    for (int c = 0; c < 4; ++c)
        ws[c] = *(const f4*)(wg + (size_t)(SK + wr) * E + (wq + c * 4) * 4);

    float4 xw[2][2], ww[2][2];
    xw[0][0] = *(const f4*)(xbuf0 + tg * 8);
    xw[0][1] = *(const f4*)(xbuf0 + tg * 8 + 4);
    ww[0][0] = *(const f4*)(wbuf0 + eg * 8);
    ww[0][1] = *(const f4*)(wbuf0 + eg * 8 + 4);
    xw[1][0] = *(const f4*)(xbuf0 + 64 + tg * 8);
    xw[1][1] = *(const f4*)(xbuf0 + 64 + tg * 8 + 4);
    ww[1][0] = *(const f4*)(wbuf0 + 64 + eg * 8);
    ww[1][1] = *(const f4*)(wbuf0 + 64 + eg * 8 + 4);

#pragma unroll 1
    for (int s = 0; s < NSTEP; ++s) {
        float* xc = (s & 1) ? xbuf1 : xbuf0;
        float* wc = (s & 1) ? wbuf1 : wbuf0;
        float* xn = (s & 1) ? xbuf0 : xbuf1;
        float* wn = (s & 1) ? wbuf0 : wbuf1;
        if (s < NSTEP - 1) {
            // write step s+1 tiles (globals issued a full step ago -> precise
            // vmcnt, fully covered). xT scatter: 16 conflict-free b32 rows.
#pragma unroll
            for (int j = 0; j < 16; ++j) xn[j * 64 + lane] = fget(xs[j >> 2], j & 3);
#pragma unroll
            for (int c = 0; c < 4; ++c)
                *(f4*)(wn + wr * 64 + (wq + c * 4) * 4) = ws[c];
            // issue step s+2 globals
            const int s2 = (s + 2 < NSTEP) ? s + 2 : NSTEP - 1;
#pragma unroll
            for (int c = 0; c < 4; ++c)
                xs[c] = *(const f4*)(xg + s2 * SK + c * 4);
#pragma unroll
            for (int c = 0; c < 4; ++c)
                ws[c] = *(const f4*)(wg + (size_t)(s2 * SK + wr) * E + (wq + c * 4) * 4);
        }
        const float* xnx = (s < NSTEP - 1) ? xn : xc;   // last step: dummy valid
        const float* wnx = (s < NSTEP - 1) ? wn : wc;
#pragma unroll
        for (int r = 0; r < 16; ++r) {
            const int p = r & 1;
            fmablock(acc, xw[p], ww[p]);               // row r (64 FMAs cover)
            // prefetch row r+2 (crosses into next step's tile for r=14,15;
            // written at the top of THIS step, 14 rows of cover, same-wave
            // in-order LDS)
            const float* xsrc = (r < 14) ? (xc + (r + 2) * 64) : (xnx + (r - 14) * 64);
            const float* wsrc = (r < 14) ? (wc + (r + 2) * 64) : (wnx + (r - 14) * 64);
            xw[p][0] = *(const f4*)(xsrc + tg * 8);
            xw[p][1] = *(const f4*)(xsrc + tg * 8 + 4);
            ww[p][0] = *(const f4*)(wsrc + eg * 8);
            ww[p][1] = *(const f4*)(wsrc + eg * 8 + 4);
        }
    }

    // ---- cross-wave K-reduction: 4 -> 2 -> 1 full-tile tree ----
    float* buf0 = smem;                  // [64][65] = 4160 floats
    float* buf1 = smem + 4160;
    __syncthreads();                     // staging slices dead
    if (w == 2) tile_store(buf0, acc, tg, eg);
    if (w == 3) tile_store(buf1, acc, tg, eg);
    __syncthreads();
    if (w == 0) tile_addin(buf0, acc, tg, eg);
    if (w == 1) tile_addin(buf1, acc, tg, eg);
    __syncthreads();
    if (w == 1) tile_store(buf0, acc, tg, eg);
    __syncthreads();
    if (w == 0) {
        tile_addin(buf0, acc, tg, eg);   // full K sum
        tile_store(buf0, acc, tg, eg);   // logits tile (pre-bias)
    }
    __syncthreads();

    float* logits = buf0;
    float* sw1 = smem + 8320; float* sw2 = smem + 8384;
    int*   si1 = (int*)(smem + 8448); int* si2 = (int*)(smem + 8512);

    if (w == 0) {
        // lane = token: top-2 scan (+bias). Strict '>' matches top_k ties.
        float m1 = -3.4e38f, m2 = -3.4e38f;
        int i1 = 0, i2 = 0;
#pragma unroll
        for (int e = 0; e < E; ++e) {
            float v = logits[lane * 65 + e] + Bv[e];
            if (v > m1)      { m2 = m1; i2 = i1; m1 = v; i1 = e; }
            else if (v > m2) { m2 = v; i2 = e; }
        }
        float p = 1.0f / (1.0f + expf(m2 - m1));   // stable: m2 <= m1
        sw1[lane] = p; sw2[lane] = 1.0f - p;
        si1[lane] = i1; si2[lane] = i2;
    }
    __syncthreads();

    // ---- coalesced float4 store of the 64x64 tile (1024 float4) ----
    float4* o4 = (float4*)(out + (size_t)tok0 * E);
#pragma unroll
    for (int p5 = 0; p5 < 4; ++p5) {
        int idx = tid + p5 * 256;
        int tl  = idx >> 4;
        int e0  = (idx & 15) * 4;
        int a1 = si1[tl], a2 = si2[tl];
        float v1 = sw1[tl], v2 = sw2[tl];
        float4 v;
        v.x = (e0 + 0 == a1) ? v1 : (e0 + 0 == a2) ? v2 : 0.0f;
        v.y = (e0 + 1 == a1) ? v1 : (e0 + 1 == a2) ? v2 : 0.0f;
        v.z = (e0 + 2 == a1) ? v1 : (e0 + 2 == a2) ? v2 : 0.0f;
        v.w = (e0 + 3 == a1) ? v1 : (e0 + 3 == a2) ? v2 : 0.0f;
        o4[idx] = v;
    }
}

extern "C" void kernel_launch(void* const* d_in, const int* in_sizes, int n_in,
                              void* d_out, int out_size, void* d_ws, size_t ws_size,
                              hipStream_t stream) {
    const float* x = (const float*)d_in[0];
    const float* W = (const float*)d_in[1];
    const float* b = (const float*)d_in[2];
    float* out = (float*)d_out;

    const int tokens = in_sizes[0] / D;      // 16384
    const int blocks = tokens / TOK;         // 256

    gating_kernel<<<blocks, THREADS, 0, stream>>>(x, W, b, out);
}